// Round 7
// baseline (20.211 us; speedup 1.0000x reference)
//
#include <hip/hip_runtime.h>
#include <math.h>

#define BLOCK 512
#define WPB 8          // waves per block
#define NGRID 1000
#define HPAD 68        // sH row stride (floats): 272B, 16B-aligned
#define W4S 68         // sW4t row stride

// broadcast lane i's value to all lanes (uniform result, literal index)
__device__ __forceinline__ float rdl(float v, int i) {
    return __uint_as_float(__builtin_amdgcn_readlane(__float_as_uint(v), i));
}
__device__ __forceinline__ float frcp(float x) { return __builtin_amdgcn_rcpf(x); }
__device__ __forceinline__ float fsqrt(float x) { return __builtin_amdgcn_sqrtf(x); }

// VGPR cap 64 (8 waves/EU) -> 32 waves/CU with 4 resident blocks.
__global__ __launch_bounds__(BLOCK, 8) void ph_kernel(
    const float* __restrict__ x,
    const float* __restrict__ W1, const float* __restrict__ b1,
    const float* __restrict__ W2, const float* __restrict__ b2,
    const float* __restrict__ W3, const float* __restrict__ b3,
    const float* __restrict__ W4, const float* __restrict__ b4,
    const float* __restrict__ kin,
    float* __restrict__ out, int B)
{
    // W2/W3 transposed + XOR-swizzled 16B granules (proven layout):
    // row j (output unit) holds column j of W; granule g stored at g^(j&7).
    __shared__ __attribute__((aligned(16))) float sW2t[64*64];
    __shared__ __attribute__((aligned(16))) float sW3t[64*64];
    __shared__ __attribute__((aligned(16))) float sW4t[6*W4S];
    __shared__ __attribute__((aligned(16))) float sH[WPB][2][HPAD];
    __shared__ float sB4[8];
    __shared__ float sLat[WPB][2][8];

    const int tid = threadIdx.x;

    for (int l = tid; l < 64*64; l += BLOCK) {
        const int i = l >> 6, j = l & 63;
        const int dst = (j << 6) + ((((i >> 2) ^ (j & 7)) << 2) | (i & 3));
        sW2t[dst] = W2[l];
        sW3t[dst] = W3[l];
    }
    for (int l = tid; l < 64*6; l += BLOCK) {
        const int i = l / 6, u = l - 6*i;
        sW4t[u*W4S + i] = W4[l];
    }
    if (tid < 8) sB4[tid] = (tid < 6) ? b4[tid] : 0.0f;
    __syncthreads();   // the only block-wide barrier

    const int lane = tid & 63;
    const int widx = tid >> 6;
    const int half = lane >> 5;
    const int la   = lane & 31;
    const int w    = blockIdx.x * WPB + widx;
    const int j    = lane;
    const int row0 = w * 2;

    const float b1j = b1[j], b2j = b2[j], b3j = b3[j];

    // x for 2 rows via lanes 0..9 (clamped), distributed by readlane
    int xidx = row0*5 + lane;
    const int xmax = B*5 - 1;
    if (xidx > xmax) xidx = xmax;
    const float xv = x[xidx];

    // ---- layer 1: 5 -> 64, exact fma chain (i ascending, bias first) ----
    float h0 = b1j, h1 = b1j;
    #pragma unroll
    for (int i = 0; i < 5; ++i) {
        const float w1i = W1[(i << 6) + j];    // coalesced, L2-hot
        h0 = fmaf(rdl(xv, i    ), w1i, h0);
        h1 = fmaf(rdl(xv, 5 + i), w1i, h1);
    }
    h0 = fmaxf(h0, 0.0f); h1 = fmaxf(h1, 0.0f);

    // ---- layers 2,3: weights from LDS (16 b128/layer), h via readlane ----
    const int swz = (j & 7) << 2;
    {
        const float* wrow = sW2t + (j << 6);
        float a0 = b2j, a1 = b2j;
        #pragma unroll
        for (int i4 = 0; i4 < 16; ++i4) {
            const float4 wv = *(const float4*)(wrow + (((i4 << 2) ^ swz)));
            const int i0 = i4 << 2;
            a0 = fmaf(rdl(h0, i0  ), wv.x, a0);
            a1 = fmaf(rdl(h1, i0  ), wv.x, a1);
            a0 = fmaf(rdl(h0, i0+1), wv.y, a0);
            a1 = fmaf(rdl(h1, i0+1), wv.y, a1);
            a0 = fmaf(rdl(h0, i0+2), wv.z, a0);
            a1 = fmaf(rdl(h1, i0+2), wv.z, a1);
            a0 = fmaf(rdl(h0, i0+3), wv.w, a0);
            a1 = fmaf(rdl(h1, i0+3), wv.w, a1);
        }
        h0 = fmaxf(a0, 0.0f); h1 = fmaxf(a1, 0.0f);
    }
    {
        const float* wrow = sW3t + (j << 6);
        float a0 = b3j, a1 = b3j;
        #pragma unroll
        for (int i4 = 0; i4 < 16; ++i4) {
            const float4 wv = *(const float4*)(wrow + (((i4 << 2) ^ swz)));
            const int i0 = i4 << 2;
            a0 = fmaf(rdl(h0, i0  ), wv.x, a0);
            a1 = fmaf(rdl(h1, i0  ), wv.x, a1);
            a0 = fmaf(rdl(h0, i0+1), wv.y, a0);
            a1 = fmaf(rdl(h1, i0+1), wv.y, a1);
            a0 = fmaf(rdl(h0, i0+2), wv.z, a0);
            a1 = fmaf(rdl(h1, i0+2), wv.z, a1);
            a0 = fmaf(rdl(h0, i0+3), wv.w, a0);
            a1 = fmaf(rdl(h1, i0+3), wv.w, a1);
        }
        h0 = fmaxf(a0, 0.0f); h1 = fmaxf(a1, 0.0f);
    }

    // ---- park h in LDS for layer 4 (same-wave write->read, in-order) ----
    sH[widx][0][j] = h0;
    sH[widx][1][j] = h1;

    // ---- layer 4: 64 -> 6, lanes 0..11 = (r = lane&1, u = lane>>1) ----
    if (lane < 12) {
        const int r = lane & 1, u = lane >> 1;
        const float* wrow = sW4t + u * W4S;
        const float* hrow = sH[widx][r];
        float acc = sB4[u];
        #pragma unroll
        for (int i4 = 0; i4 < 16; ++i4) {
            const float4 wv = *(const float4*)(wrow + (i4 << 2));
            const float4 hv = *(const float4*)(hrow + (i4 << 2));
            acc = fmaf(hv.x, wv.x, acc); acc = fmaf(hv.y, wv.y, acc);
            acc = fmaf(hv.z, wv.z, acc); acc = fmaf(hv.w, wv.w, acc);
        }
        sLat[widx][r][u] = acc;
    }

    const float i00 = kin[0], i01 = kin[1], i02 = kin[2];
    const float invRT = 1.0f / 2478.8191f;
    const float ksr0 = ((-kin[3]) * 96485.33f) * invRT;
    const float ksr1 = ((-kin[4]) * 96485.33f) * invRT;
    const float ksr2 = ((-kin[5]) * 96485.33f) * invRT;
    const float stepV = 1.25f / 999.0f;

    const int row = row0 + half;
    const bool act = (row < B);

    // ---- physics: lanes {0,32} each run one row's chain ----
    float c0v = 0.0f, c1v = 0.0f, c2v = 0.0f, l0v = 0.0f, l1v = 0.0f;
    if (la == 0) {
        const int rowc = act ? row : (B - 1);
        const float* plat = sLat[widx][half];
        const float lat0 = plat[0], lat1 = plat[1], lat2 = plat[2];
        const float lat3 = plat[3], lat4 = plat[4], lat5 = plat[5];
        const float rr   = 4e-8f * __expf(lat0);
        const float epsv = frcp(1.0f + __expf(-lat1));
        const float zlt  = x[rowc*5 + 3];
        const float Lf   = zlt * frcp(1.0f - epsv);
        const float Kdl  = __expf(lat2);
        const float z0 = 2.0f*lat3, z1 = 2.0f*lat4, z2 = 2.0f*lat5;
        const float mz = fmaxf(z0, fmaxf(z1, z2));
        const float p0 = __expf(z0 - mz), p1 = __expf(z1 - mz), p2 = __expf(z2 - mz);
        const float ips = frcp(p0 + p1 + p2);
        const float th0 = p0*ips, th1 = p1*ips, th2 = p2*ips;
        const float irr = frcp(rr);
        const float gdl   = (Kdl * 1.91e-9f) * (epsv * fsqrt(epsv)) * irr;
        const float asurf = (3.0f * (1.0f - epsv)) * Lf * irr;
        c0v = (i00*th0)*asurf; c1v = (i01*th1)*asurf; c2v = (i02*th2)*asurf;
        const float il0 = (((2.0f*96485.33f)*34.0f)*gdl)*0.1f;
        const float il1 = (((12.0f*96485.33f)*34.0f)*gdl)*0.1f;
        l0v = frcp(il0); l1v = frcp(il1);
    }
    // broadcast row constants within each half (bit-exact)
    const int src = half << 5;
    const float c0    = __shfl(c0v, src, 64);
    const float c1    = __shfl(c1v, src, 64);
    const float c2    = __shfl(c2v, src, 64);
    const float invl0 = __shfl(l0v, src, 64);
    const float invl1 = __shfl(l1v, src, 64);

    auto evaltot = [&](int v) -> float {
        const float V = -1.25f + stepV * (float)v;
        const float t0 = __expf(ksr0 * (V + 0.11f));
        const float t1 = __expf(ksr1 * (V - 0.08f));
        const float t2 = __expf(ksr2 * V);
        const float ie0 = frcp(frcp(c0*t0) + invl0);
        const float ie1 = frcp(frcp(c1*t1) + invl1);
        const float ie2 = c2*t2;       // i_lim[2] = inf
        return ie0 + ie1 + ie2;
    };

    // coarse: 32 points stride 32; i_tot weakly decreasing in v
    const int vc = la << 5;            // 0..992
    const float totc = evaltot(vc);
    float bd = fabsf(totc - 200.0f);
    int bidx = vc;

    const unsigned long long mall = __ballot(totc >= 200.0f);
    const unsigned int m32 = (unsigned int)(mall >> (half << 5));
    const int kstar = m32 ? (31 - __builtin_clz(m32)) : 0;
    const int base = kstar << 5;

    // fine: 32 points (base, base+32]; coarse candidates cover the rest
    {
        int vf = base + 1 + la;
        if (vf > NGRID-1) vf = NGRID-1;
        const float totf = evaltot(vf);
        const float df = fabsf(totf - 200.0f);
        if (df < bd || (df == bd && vf < bidx)) { bd = df; bidx = vf; }
    }

    // lexicographic (d, idx) butterfly within each 32-lane half
    #pragma unroll
    for (int off = 16; off; off >>= 1) {
        const float od = __shfl_xor(bd, off, 64);
        const int   oi = __shfl_xor(bidx, off, 64);
        if (od < bd || (od == bd && oi < bidx)) { bd = od; bidx = oi; }
    }

    // ---- select + FE ----
    const float V = -1.25f + stepV * (float)bidx;
    const float t0 = __expf(ksr0 * (V + 0.11f));
    const float t1 = __expf(ksr1 * (V - 0.08f));
    const float t2 = __expf(ksr2 * V);
    const float ie0 = frcp(frcp(c0*t0) + invl0);
    const float ie1 = frcp(frcp(c1*t1) + invl1);
    const float ie2 = c2*t2;
    const float itr = frcp(ie0 + ie1 + ie2);
    if (act && la < 2) {
        out[row*2 + la] = (la == 0) ? (ie1*itr) : (ie0*itr);
    }
}

extern "C" void kernel_launch(void* const* d_in, const int* in_sizes, int n_in,
                              void* d_out, int out_size, void* d_ws, size_t ws_size,
                              hipStream_t stream) {
    const float* x   = (const float*)d_in[0];
    const float* W1  = (const float*)d_in[1];
    const float* b1  = (const float*)d_in[2];
    const float* W2  = (const float*)d_in[3];
    const float* b2  = (const float*)d_in[4];
    const float* W3  = (const float*)d_in[5];
    const float* b3  = (const float*)d_in[6];
    const float* W4  = (const float*)d_in[7];
    const float* b4  = (const float*)d_in[8];
    const float* kin = (const float*)d_in[9];
    float* out = (float*)d_out;
    const int B = in_sizes[0] / 5;

    // 16 rows per block (8 waves x 2 rows): B=16384 -> 1024 blocks
    // = 4 resident blocks/CU (39.3 KB LDS, VGPR<=64) = 32 waves/CU.
    const int grid = (B + WPB*2 - 1) / (WPB*2);
    ph_kernel<<<grid, BLOCK, 0, stream>>>(x, W1, b1, W2, b2, W3, b3, W4, b4, kin, out, B);
}